// Round 2
// baseline (411.973 us; speedup 1.0000x reference)
//
#include <hip/hip_runtime.h>

// ConfidenceProtoSegHead v2: sim = x(131072x256) . protosT(256x190), max over 10,
// LayerNorm over 19, write [b,19,h,w].
// Split bf16: x=xh+xl, p=ph+pl; sim ~= xh.ph + xl.ph + xh.pl (fp32 MFMA accum).
//
// v2 changes vs v1 (latency/occupancy theory):
//  - 32x32x16 MFMA (2495 vs 2075 TF pipe rate, half the instructions)
//  - LDS 80KB -> 40KB (single-buffered A16K + B24K), 4 blocks/CU, grid fully resident
//  - B reg-staged (no global_load_lds -> no vmcnt(0) drain at barriers)
//  - A loads float2 pixel-pairs; pixel<->row permutation keeps LDS writes contiguous
//  - 2-phase chunk loop: [issue loads; MFMA] rawbar [stage writes] syncthreads

#define CC_   256
#define HW_   32768
#define NPIX_ 131072
#define NCLS_ 19
#define MBLK_ 128
#define SIMST_ 194            // padded f32 stride for epilogue sims tile

typedef __attribute__((ext_vector_type(8)))  short bf16x8;
typedef __attribute__((ext_vector_type(16))) float f32x16;
typedef __attribute__((ext_vector_type(4)))  float f32x4;
typedef __attribute__((ext_vector_type(2)))  float f32x2;
typedef __attribute__((ext_vector_type(4)))  unsigned int u32x4;

// compute->stage barrier: all LDS reads done, but global loads stay in flight
#define RAWBAR() do {                                          \
  __builtin_amdgcn_sched_barrier(0);                           \
  asm volatile("s_waitcnt lgkmcnt(0)" ::: "memory");           \
  __builtin_amdgcn_s_barrier();                                \
  asm volatile("" ::: "memory");                               \
  __builtin_amdgcn_sched_barrier(0);                           \
} while (0)

// ---------------- K1: normalize + pack prototypes (32x32 B-frag order) -----
// Bp layout (16B units): (((cc*2+ks)*6 + nt)*2 + part)*64 + koct*32 + cL
// frag semantics: lane L -> col = nt*32 + (L&31); k-octet = L>>5; elem i -> k=koct*8+i
__global__ void prep_protos(const float* __restrict__ protos, char* __restrict__ Bp) {
  const int p = blockIdx.x;     // proto column 0..191 (190,191 = zero pad)
  const int l = threadIdx.x;    // 0..63
  __shared__ float pn[256];
  float v[4] = {0.f, 0.f, 0.f, 0.f};
  float sq = 0.f;
  if (p < 190) {
    #pragma unroll
    for (int i = 0; i < 4; ++i) {
      v[i] = protos[p * 256 + l * 4 + i];
      sq += v[i] * v[i];
    }
  }
  #pragma unroll
  for (int off = 32; off > 0; off >>= 1) sq += __shfl_xor(sq, off, 64);
  const float scale = (p < 190) ? 1.0f / (sqrtf(sq) + 1e-12f) : 0.0f;
  #pragma unroll
  for (int i = 0; i < 4; ++i) pn[l * 4 + i] = v[i] * scale;
  __syncthreads();

  const int oct  = l >> 1;      // c-octet 0..31
  const int part = l & 1;       // 0=hi 1=lo
  unsigned int w[4];
  #pragma unroll
  for (int pr = 0; pr < 4; ++pr) {
    const float f0 = pn[oct * 8 + 2 * pr];
    const float f1 = pn[oct * 8 + 2 * pr + 1];
    const unsigned int u0 = __builtin_bit_cast(unsigned int, f0);
    const unsigned int u1 = __builtin_bit_cast(unsigned int, f1);
    if (part == 0) {
      w[pr] = (u1 & 0xFFFF0000u) | (u0 >> 16);
    } else {
      const float t0 = __builtin_bit_cast(float, u0 & 0xFFFF0000u);
      const float t1 = __builtin_bit_cast(float, u1 & 0xFFFF0000u);
      const unsigned int v0 = __builtin_bit_cast(unsigned int, f0 - t0);
      const unsigned int v1 = __builtin_bit_cast(unsigned int, f1 - t1);
      w[pr] = (v1 & 0xFFFF0000u) | (v0 >> 16);
    }
  }
  const int cc = oct >> 2, ks = (oct >> 1) & 1, ko = oct & 1;
  const int nt = p >> 5, cL = p & 31;
  const size_t a16 = (size_t)((((cc * 2 + ks) * 6 + nt) * 2 + part) * 64 + ko * 32 + cL);
  *(u32x4*)(Bp + a16 * 16) = (u32x4){w[0], w[1], w[2], w[3]};
}

// ---------------- K2: fused GEMM + max + LayerNorm -------------------------
// A LDS (16KB, 16B units): ((ks*2+part)*4 + mt)*64 + koct*32 + row
//   pixel perm within mt: row = ((pix&1)<<4) | (pix>>1)  (pix in 0..31)
// B LDS (24KB): (ks*12 + nt*2 + part)*64 + L   (flat copy of Bp chunk)
__device__ __forceinline__ void stageA(char* Albase, const f32x2* aLd,
                                       int ksw, int kow, int mtw, int r15w) {
  #pragma unroll
  for (int e = 0; e < 2; ++e) {          // pixel parity: pix = 2*lane + e
    unsigned int wh[4], wl[4];
    #pragma unroll
    for (int pr = 0; pr < 4; ++pr) {
      const float f0 = aLd[2 * pr][e];
      const float f1 = aLd[2 * pr + 1][e];
      const unsigned int u0 = __builtin_bit_cast(unsigned int, f0);
      const unsigned int u1 = __builtin_bit_cast(unsigned int, f1);
      wh[pr] = (u1 & 0xFFFF0000u) | (u0 >> 16);
      const float t0 = __builtin_bit_cast(float, u0 & 0xFFFF0000u);
      const float t1 = __builtin_bit_cast(float, u1 & 0xFFFF0000u);
      const unsigned int v0 = __builtin_bit_cast(unsigned int, f0 - t0);
      const unsigned int v1 = __builtin_bit_cast(unsigned int, f1 - t1);
      wl[pr] = (v1 & 0xFFFF0000u) | (v0 >> 16);
    }
    // row = e*16 + (lane&15); slot = koct*32 + row
    char* bh = Albase + (size_t)((((ksw * 2 + 0) * 4 + mtw) * 64 + kow * 32 + e * 16 + r15w) * 16);
    char* bl = Albase + (size_t)((((ksw * 2 + 1) * 4 + mtw) * 64 + kow * 32 + e * 16 + r15w) * 16);
    *(u32x4*)bh = (u32x4){wh[0], wh[1], wh[2], wh[3]};
    *(u32x4*)bl = (u32x4){wl[0], wl[1], wl[2], wl[3]};
  }
}

__launch_bounds__(256, 4)
__global__ void gemm_kernel(const float* __restrict__ x, const char* __restrict__ Bp,
                            const float* __restrict__ mw, const float* __restrict__ mb,
                            float* __restrict__ out) {
  __shared__ __align__(16) char smem[40960];
  char* Albase = smem;            // 16 KB
  char* Blbase = smem + 16384;    // 24 KB

  const int tid  = threadIdx.x;
  const int wave = tid >> 6;
  const int lane = tid & 63;
  const int n0   = blockIdx.x * MBLK_;
  const int b    = n0 >> 15;
  const int hw0  = n0 & (HW_ - 1);
  const float* xb = x + (size_t)b * CC_ * HW_ + hw0;

  // A staging ownership: wave = c-octet, lane = pixel-pair
  const int oct  = wave;
  const int ksw  = oct >> 1, kow = oct & 1;
  const int mtw  = lane >> 4, r15w = lane & 15;
  const float* xA = xb + (size_t)(oct * 8) * HW_ + 2 * lane;

  f32x16 acc[6];
  #pragma unroll
  for (int nt = 0; nt < 6; ++nt) acc[nt] = (f32x16)(0.0f);

  f32x2 aLd[8];
  f32x4 bLd[6];

  // ---- prologue: load + stage chunk 0
  #pragma unroll
  for (int j = 0; j < 8; ++j) aLd[j] = *(const f32x2*)(xA + (size_t)j * HW_);
  #pragma unroll
  for (int i = 0; i < 6; ++i) bLd[i] = *(const f32x4*)(Bp + (size_t)(tid + 256 * i) * 16);
  stageA(Albase, aLd, ksw, kow, mtw, r15w);
  #pragma unroll
  for (int i = 0; i < 6; ++i) *(f32x4*)(Blbase + (size_t)(tid + 256 * i) * 16) = bLd[i];
  __syncthreads();

  #pragma unroll
  for (int cc = 0; cc < 8; ++cc) {
    // issue next-chunk loads first (latency hides under MFMA phase)
    if (cc < 7) {
      const float* xAn = xA + (size_t)((cc + 1) * 32) * HW_;
      #pragma unroll
      for (int j = 0; j < 8; ++j) aLd[j] = *(const f32x2*)(xAn + (size_t)j * HW_);
      #pragma unroll
      for (int i = 0; i < 6; ++i)
        bLd[i] = *(const f32x4*)(Bp + (size_t)(1536 * (cc + 1) + tid + 256 * i) * 16);
    }
    // ---- MFMA phase on current LDS contents
    #pragma unroll
    for (int ks = 0; ks < 2; ++ks) {
      const bf16x8 ah = *(const bf16x8*)(Albase + (size_t)((((ks * 2 + 0) * 4 + wave) * 64 + lane) * 16));
      const bf16x8 al = *(const bf16x8*)(Albase + (size_t)((((ks * 2 + 1) * 4 + wave) * 64 + lane) * 16));
      #pragma unroll
      for (int nt = 0; nt < 6; ++nt) {
        const bf16x8 bh = *(const bf16x8*)(Blbase + (size_t)(((ks * 12 + nt * 2 + 0) * 64 + lane) * 16));
        const bf16x8 bl = *(const bf16x8*)(Blbase + (size_t)(((ks * 12 + nt * 2 + 1) * 64 + lane) * 16));
        acc[nt] = __builtin_amdgcn_mfma_f32_32x32x16_bf16(ah, bh, acc[nt], 0, 0, 0);
        acc[nt] = __builtin_amdgcn_mfma_f32_32x32x16_bf16(al, bh, acc[nt], 0, 0, 0);
        acc[nt] = __builtin_amdgcn_mfma_f32_32x32x16_bf16(ah, bl, acc[nt], 0, 0, 0);
      }
    }
    RAWBAR();                       // reads done; loads still in flight
    if (cc < 7) {
      stageA(Albase, aLd, ksw, kow, mtw, r15w);
      #pragma unroll
      for (int i = 0; i < 6; ++i) *(f32x4*)(Blbase + (size_t)(tid + 256 * i) * 16) = bLd[i];
    }
    __syncthreads();                // publish (vmcnt naturally drained: loads consumed)
  }

  // ---- epilogue: 4 rounds of 32 pixels through LDS
  float* sims = (float*)smem;       // [32][SIMST_]  (24.8 KB <= 40 KB)
  #pragma unroll 1
  for (int r = 0; r < 4; ++r) {
    if (wave == r) {
      #pragma unroll
      for (int nt = 0; nt < 6; ++nt) {
        #pragma unroll
        for (int q = 0; q < 16; ++q) {
          const int row = (q & 3) + 8 * (q >> 2) + 4 * (lane >> 5);
          sims[row * SIMST_ + nt * 32 + (lane & 31)] = acc[nt][q];
        }
      }
    }
    __syncthreads();
    if (tid < 32) {
      float mx[NCLS_];
      #pragma unroll
      for (int k = 0; k < NCLS_; ++k) {
        const float* rp = sims + tid * SIMST_ + k * 10;
        const f32x2 v0 = *(const f32x2*)(rp + 0);
        const f32x2 v1 = *(const f32x2*)(rp + 2);
        const f32x2 v2 = *(const f32x2*)(rp + 4);
        const f32x2 v3 = *(const f32x2*)(rp + 6);
        const f32x2 v4 = *(const f32x2*)(rp + 8);
        float m01 = fmaxf(fmaxf(v0[0], v0[1]), fmaxf(v1[0], v1[1]));
        float m23 = fmaxf(fmaxf(v2[0], v2[1]), fmaxf(v3[0], v3[1]));
        mx[k] = fmaxf(fmaxf(m01, m23), fmaxf(v4[0], v4[1]));
      }
      float mu = 0.f;
      #pragma unroll
      for (int k = 0; k < NCLS_; ++k) mu += mx[k];
      mu *= (1.0f / NCLS_);
      float var = 0.f;
      #pragma unroll
      for (int k = 0; k < NCLS_; ++k) { const float d = mx[k] - mu; var += d * d; }
      var *= (1.0f / NCLS_);
      const float rstd = rsqrtf(var + 1e-5f);
      // un-permute: sims-row t -> pixel r*32 + ((t&15)<<1) + ((t>>4)&1)
      const int hw = hw0 + r * 32 + ((tid & 15) << 1) + ((tid >> 4) & 1);
      #pragma unroll
      for (int k = 0; k < NCLS_; ++k) {
        out[((size_t)(b * NCLS_ + k) << 15) + hw] = (mx[k] - mu) * rstd * mw[k] + mb[k];
      }
    }
    __syncthreads();
  }
}

extern "C" void kernel_launch(void* const* d_in, const int* in_sizes, int n_in,
                              void* d_out, int out_size, void* d_ws, size_t ws_size,
                              hipStream_t stream) {
  const float* x      = (const float*)d_in[0];
  const float* protos = (const float*)d_in[1];
  const float* mw     = (const float*)d_in[2];
  const float* mb     = (const float*)d_in[3];
  float* out = (float*)d_out;
  char* Bp   = (char*)d_ws;       // 192 KB packed prototypes

  prep_protos<<<192, 64, 0, stream>>>(protos, Bp);
  gemm_kernel<<<NPIX_ / MBLK_, 256, 0, stream>>>(x, Bp, mw, mb, out);
}

// Round 3
// 204.145 us; speedup vs baseline: 2.0180x; 2.0180x over previous
//
#include <hip/hip_runtime.h>

// ConfidenceProtoSegHead v3: sim = x(131072x256) . protosT(256x190), max over 10,
// LayerNorm over 19, write [b,19,h,w].
// Split bf16: x=xh+xl, p=ph+pl; sim ~= xh.ph + xl.ph + xh.pl (fp32 MFMA accum).
//
// v3 vs v2: fix the VGPR spill (v2: launch_bounds(256,4) forced 128-cap on ~190-reg
// kernel -> 500MB scratch traffic, MfmaUtil 5.6%).
//  - 512-thr blocks, 8 waves = 4 rowgrp x 2 colgrp; acc = 3 x f32x16 = 48 VGPR/wave
//  - B staged via global_load_lds (double-buffered 2x24KB): no bLd regs, no vmcnt
//    drain inside the phase (drains at publish syncthreads, covered by MFMA phase)
//  - A single-buffered reg-staged (16KB); LDS total 64KB -> 2 blocks/CU, 16 waves/CU
//  - launch_bounds(512,4): VGPR cap 128, est. use ~115

#define CC_   256
#define HW_   32768
#define NPIX_ 131072
#define NCLS_ 19
#define MBLK_ 128
#define SIMST_ 194            // padded f32 stride for epilogue sims tile

typedef __attribute__((ext_vector_type(8)))  short bf16x8;
typedef __attribute__((ext_vector_type(16))) float f32x16;
typedef __attribute__((ext_vector_type(4)))  float f32x4;
typedef __attribute__((ext_vector_type(2)))  float f32x2;
typedef __attribute__((ext_vector_type(4)))  unsigned int u32x4;
typedef __attribute__((ext_vector_type(2)))  unsigned int u32x2;

__device__ __forceinline__ void gll16(const void* g, void* l) {
  __builtin_amdgcn_global_load_lds((__attribute__((address_space(1))) void*)(g),
                                   (__attribute__((address_space(3))) void*)(l), 16, 0, 0);
}

// compute->stage barrier: LDS reads done; global loads / glls stay in flight
#define RAWBAR() do {                                          \
  __builtin_amdgcn_sched_barrier(0);                           \
  asm volatile("s_waitcnt lgkmcnt(0)" ::: "memory");           \
  __builtin_amdgcn_s_barrier();                                \
  asm volatile("" ::: "memory");                               \
  __builtin_amdgcn_sched_barrier(0);                           \
} while (0)

// ---------------- K1: normalize + pack prototypes (32x32 B-frag order) -----
// Bp layout (16B units): (((cc*2+ks)*6 + nt)*2 + part)*64 + koct*32 + cL
// frag semantics: lane L -> col = nt*32 + (L&31); k-octet = L>>5; elem i -> k=koct*8+i
__global__ void prep_protos(const float* __restrict__ protos, char* __restrict__ Bp) {
  const int p = blockIdx.x;     // proto column 0..191 (190,191 = zero pad)
  const int l = threadIdx.x;    // 0..63
  __shared__ float pn[256];
  float v[4] = {0.f, 0.f, 0.f, 0.f};
  float sq = 0.f;
  if (p < 190) {
    #pragma unroll
    for (int i = 0; i < 4; ++i) {
      v[i] = protos[p * 256 + l * 4 + i];
      sq += v[i] * v[i];
    }
  }
  #pragma unroll
  for (int off = 32; off > 0; off >>= 1) sq += __shfl_xor(sq, off, 64);
  const float scale = (p < 190) ? 1.0f / (sqrtf(sq) + 1e-12f) : 0.0f;
  #pragma unroll
  for (int i = 0; i < 4; ++i) pn[l * 4 + i] = v[i] * scale;
  __syncthreads();

  const int oct  = l >> 1;      // c-octet 0..31
  const int part = l & 1;       // 0=hi 1=lo
  unsigned int w[4];
  #pragma unroll
  for (int pr = 0; pr < 4; ++pr) {
    const float f0 = pn[oct * 8 + 2 * pr];
    const float f1 = pn[oct * 8 + 2 * pr + 1];
    const unsigned int u0 = __builtin_bit_cast(unsigned int, f0);
    const unsigned int u1 = __builtin_bit_cast(unsigned int, f1);
    if (part == 0) {
      w[pr] = (u1 & 0xFFFF0000u) | (u0 >> 16);
    } else {
      const float t0 = __builtin_bit_cast(float, u0 & 0xFFFF0000u);
      const float t1 = __builtin_bit_cast(float, u1 & 0xFFFF0000u);
      const unsigned int v0 = __builtin_bit_cast(unsigned int, f0 - t0);
      const unsigned int v1 = __builtin_bit_cast(unsigned int, f1 - t1);
      w[pr] = (v1 & 0xFFFF0000u) | (v0 >> 16);
    }
  }
  const int cc = oct >> 2, ks = (oct >> 1) & 1, ko = oct & 1;
  const int nt = p >> 5, cL = p & 31;
  const size_t a16 = (size_t)((((cc * 2 + ks) * 6 + nt) * 2 + part) * 64 + ko * 32 + cL);
  *(u32x4*)(Bp + a16 * 16) = (u32x4){w[0], w[1], w[2], w[3]};
}

// ---------------- K2: fused GEMM + max + LayerNorm -------------------------
// A LDS (16KB, 16B units): ((ks*2+part)*4 + mt)*64 + koct*32 + row
//   pixel perm within mt: row = ((pix&1)<<4) | (pix>>1)  (pix in 0..31)
// B LDS (2 x 24KB): flat copy of Bp chunk, (ks*12 + nt*2 + part)*64 + L
// Staging ownership: wave w owns channels w*4..w*4+3 of the chunk;
//   lane = pixel-pair (pix = 2*lane+e). ks=w>>2, koct=(w>>1)&1, sub=w&1.
__device__ __forceinline__ void stageA(char* Albase, const f32x2* aLd,
                                       int ksw, int kow, int sub, int mtw, int r15w) {
  #pragma unroll
  for (int e = 0; e < 2; ++e) {
    unsigned int wh[2], wl[2];
    #pragma unroll
    for (int q = 0; q < 2; ++q) {
      const float f0 = aLd[2 * q][e];
      const float f1 = aLd[2 * q + 1][e];
      const unsigned int u0 = __builtin_bit_cast(unsigned int, f0);
      const unsigned int u1 = __builtin_bit_cast(unsigned int, f1);
      wh[q] = (u1 & 0xFFFF0000u) | (u0 >> 16);
      const float t0 = __builtin_bit_cast(float, u0 & 0xFFFF0000u);
      const float t1 = __builtin_bit_cast(float, u1 & 0xFFFF0000u);
      const unsigned int v0 = __builtin_bit_cast(unsigned int, f0 - t0);
      const unsigned int v1 = __builtin_bit_cast(unsigned int, f1 - t1);
      wl[q] = (v1 & 0xFFFF0000u) | (v0 >> 16);
    }
    const int slotH = ((ksw * 2 + 0) * 4 + mtw) * 64 + kow * 32 + e * 16 + r15w;
    const int slotL = ((ksw * 2 + 1) * 4 + mtw) * 64 + kow * 32 + e * 16 + r15w;
    *(u32x2*)(Albase + slotH * 16 + sub * 8) = (u32x2){wh[0], wh[1]};
    *(u32x2*)(Albase + slotL * 16 + sub * 8) = (u32x2){wl[0], wl[1]};
  }
}

__launch_bounds__(512, 4)
__global__ void gemm_kernel(const float* __restrict__ x, const char* __restrict__ Bp,
                            const float* __restrict__ mw, const float* __restrict__ mb,
                            float* __restrict__ out) {
  __shared__ __align__(16) char smem[65536];
  char* Albase = smem;            // 16 KB
  char* Blbase = smem + 16384;    // 2 x 24 KB

  const int tid  = threadIdx.x;
  const int wave = tid >> 6;
  const int lane = tid & 63;
  const int n0   = blockIdx.x * MBLK_;
  const int b    = n0 >> 15;
  const int hw0  = n0 & (HW_ - 1);
  const float* xb = x + (size_t)b * CC_ * HW_ + hw0;

  // staging ids
  const int ksw = wave >> 2, kow = (wave >> 1) & 1, sub = wave & 1;
  const int mtw = lane >> 4, r15w = lane & 15;
  const float* xA = xb + (size_t)(wave * 4) * HW_ + 2 * lane;

  // compute ids
  const int rowg = wave >> 1, colg = wave & 1;

  f32x16 acc[3];
  #pragma unroll
  for (int nt = 0; nt < 3; ++nt) acc[nt] = (f32x16)(0.0f);

  f32x2 aLd[4];

  // ---- prologue: chunk 0
  #pragma unroll
  for (int j = 0; j < 4; ++j) aLd[j] = *(const f32x2*)(xA + (size_t)j * HW_);
  #pragma unroll
  for (int i = 0; i < 3; ++i)
    gll16(Bp + (size_t)(tid + 512 * i) * 16, Blbase + (tid + 512 * i) * 16);
  stageA(Albase, aLd, ksw, kow, sub, mtw, r15w);
  __syncthreads();

  #pragma unroll
  for (int cc = 0; cc < 8; ++cc) {
    const int buf = cc & 1;
    // issue next-chunk loads first (latency hides under MFMA phase)
    if (cc < 7) {
      const float* xn = xA + (size_t)((cc + 1) * 32) * HW_;
      #pragma unroll
      for (int j = 0; j < 4; ++j) aLd[j] = *(const f32x2*)(xn + (size_t)j * HW_);
      #pragma unroll
      for (int i = 0; i < 3; ++i)
        gll16(Bp + (size_t)((cc + 1) * 1536 + tid + 512 * i) * 16,
              Blbase + (buf ^ 1) * 24576 + (tid + 512 * i) * 16);
    }
    // ---- MFMA phase
    const char* Bq = Blbase + buf * 24576;
    #pragma unroll
    for (int ks = 0; ks < 2; ++ks) {
      const bf16x8 ah = *(const bf16x8*)(Albase + (size_t)((((ks * 2 + 0) * 4 + rowg) * 64 + lane) * 16));
      const bf16x8 al = *(const bf16x8*)(Albase + (size_t)((((ks * 2 + 1) * 4 + rowg) * 64 + lane) * 16));
      #pragma unroll
      for (int nt = 0; nt < 3; ++nt) {
        const int ntg = colg * 3 + nt;
        const bf16x8 bh = *(const bf16x8*)(Bq + (size_t)(((ks * 12 + ntg * 2 + 0) * 64 + lane) * 16));
        const bf16x8 bl = *(const bf16x8*)(Bq + (size_t)(((ks * 12 + ntg * 2 + 1) * 64 + lane) * 16));
        acc[nt] = __builtin_amdgcn_mfma_f32_32x32x16_bf16(ah, bh, acc[nt], 0, 0, 0);
        acc[nt] = __builtin_amdgcn_mfma_f32_32x32x16_bf16(al, bh, acc[nt], 0, 0, 0);
        acc[nt] = __builtin_amdgcn_mfma_f32_32x32x16_bf16(ah, bl, acc[nt], 0, 0, 0);
      }
    }
    RAWBAR();                       // lgkm only: A-loads + B-glls stay in flight
    if (cc < 7) stageA(Albase, aLd, ksw, kow, sub, mtw, r15w);
    __syncthreads();                // drains vmcnt (B glls long since landed)
  }

  // ---- epilogue: 2 rounds of 64 pixels through LDS
  float* sims = (float*)smem;       // [64][SIMST_] = 48.5 KB (aliases A/B, all reads done)
  #pragma unroll 1
  for (int r = 0; r < 2; ++r) {
    if ((rowg >> 1) == r) {
      const int srow = (rowg & 1) * 32;
      #pragma unroll
      for (int nt = 0; nt < 3; ++nt) {
        #pragma unroll
        for (int q = 0; q < 16; ++q) {
          const int row = (q & 3) + 8 * (q >> 2) + 4 * (lane >> 5);
          sims[(srow + row) * SIMST_ + (colg * 3 + nt) * 32 + (lane & 31)] = acc[nt][q];
        }
      }
    }
    __syncthreads();
    if (tid < 64) {
      float mx[NCLS_];
      #pragma unroll
      for (int k = 0; k < NCLS_; ++k) {
        const float* rp = sims + tid * SIMST_ + k * 10;
        const f32x2 v0 = *(const f32x2*)(rp + 0);
        const f32x2 v1 = *(const f32x2*)(rp + 2);
        const f32x2 v2 = *(const f32x2*)(rp + 4);
        const f32x2 v3 = *(const f32x2*)(rp + 6);
        const f32x2 v4 = *(const f32x2*)(rp + 8);
        float m01 = fmaxf(fmaxf(v0[0], v0[1]), fmaxf(v1[0], v1[1]));
        float m23 = fmaxf(fmaxf(v2[0], v2[1]), fmaxf(v3[0], v3[1]));
        mx[k] = fmaxf(fmaxf(m01, m23), fmaxf(v4[0], v4[1]));
      }
      float mu = 0.f;
      #pragma unroll
      for (int k = 0; k < NCLS_; ++k) mu += mx[k];
      mu *= (1.0f / NCLS_);
      float var = 0.f;
      #pragma unroll
      for (int k = 0; k < NCLS_; ++k) { const float d = mx[k] - mu; var += d * d; }
      var *= (1.0f / NCLS_);
      const float rstd = rsqrtf(var + 1e-5f);
      // un-permute: sims-row t -> pixel (2r + (t>>5))*32 + ((t&15)<<1) + ((t>>4)&1)
      const int s = tid & 31;
      const int hw = hw0 + (2 * r + (tid >> 5)) * 32 + ((s & 15) << 1) + (s >> 4);
      #pragma unroll
      for (int k = 0; k < NCLS_; ++k) {
        out[((size_t)(b * NCLS_ + k) << 15) + hw] = (mx[k] - mu) * rstd * mw[k] + mb[k];
      }
    }
    __syncthreads();
  }
}

extern "C" void kernel_launch(void* const* d_in, const int* in_sizes, int n_in,
                              void* d_out, int out_size, void* d_ws, size_t ws_size,
                              hipStream_t stream) {
  const float* x      = (const float*)d_in[0];
  const float* protos = (const float*)d_in[1];
  const float* mw     = (const float*)d_in[2];
  const float* mb     = (const float*)d_in[3];
  float* out = (float*)d_out;
  char* Bp   = (char*)d_ws;       // 192 KB packed prototypes

  prep_protos<<<192, 64, 0, stream>>>(protos, Bp);
  gemm_kernel<<<NPIX_ / MBLK_, 512, 0, stream>>>(x, Bp, mw, mb, out);
}